// Round 4
// baseline (5806.306 us; speedup 1.0000x reference)
//
#include <hip/hip_runtime.h>
#include <stdint.h>

#define HH 256
#define SS 2048
#define BB 256
#define DD 64
#define NG 16

typedef __attribute__((ext_vector_type(8))) short bh8;
typedef __attribute__((ext_vector_type(4))) float fx4;
typedef __attribute__((ext_vector_type(4))) float f4v;

// ws layout (bytes):
#define VOTE_OFF  0                       // 512 x u32 (sc0sc1 only -> packing ok)
#define TAG0_OFF  4096                    // 16 groups x 128B (one full line each)
#define TAG1_OFF  8192                    // 16 groups x 128B
#define PRB_OFF   16384                   // 512 blocks x 128B probe cells
#define MEMSET_SZ 81920
#define YS_OFF    131072ull
#define RING_OFF  (131072ull + 268435456ull)
#define WS_NEED   (RING_OFF + 262144ull)

__device__ __forceinline__ short f2bf(float f) {
  uint32_t u = __builtin_bit_cast(uint32_t, f);
  u += 0x7FFFu + ((u >> 16) & 1u);
  return (short)(u >> 16);
}
__device__ __forceinline__ float bf2f(short s) {
  uint32_t u = ((uint32_t)(uint16_t)s) << 16;
  return __builtin_bit_cast(float, u);
}
__device__ __forceinline__ float sigm_(float x) {
  x = fminf(fmaxf(x, -30.f), 30.f);
  return 1.0f / (1.0f + __expf(-x));
}
__device__ __forceinline__ float tanh_(float x) {
  x = fminf(fmaxf(x, -15.f), 15.f);
  float e = __expf(2.0f * x);
  return (e - 1.0f) / (e + 1.0f);
}
__device__ __forceinline__ fx4 mfma16(bh8 a, bh8 b, fx4 c) {
  return __builtin_amdgcn_mfma_f32_16x16x32_bf16(a, b, c, 0, 0, 0);
}
__device__ __forceinline__ bh8 cvt8(f4v a, f4v b) {
  bh8 r;
  r[0]=f2bf(a[0]); r[1]=f2bf(a[1]); r[2]=f2bf(a[2]); r[3]=f2bf(a[3]);
  r[4]=f2bf(b[0]); r[5]=f2bf(b[1]); r[6]=f2bf(b[2]); r[7]=f2bf(b[3]);
  return r;
}

// S1=true: coherence point (MALL, cross-XCD safe, round-2 proven).
// S1=false: sc0-only (XCD-local L2) — used ONLY after the runtime probe passes.
template<bool S1> __device__ __forceinline__ bh8 gload(const short* p) {
  bh8 r;
  if constexpr (S1) asm volatile("global_load_dwordx4 %0, %1, off sc0 sc1" : "=v"(r) : "v"(p));
  else              asm volatile("global_load_dwordx4 %0, %1, off sc0"     : "=v"(r) : "v"(p));
  return r;
}
template<bool S1> __device__ __forceinline__ uint32_t ldw(const uint32_t* p) {
  uint32_t r;
  if constexpr (S1) asm volatile("global_load_dword %0, %1, off sc0 sc1" : "=v"(r) : "v"(p));
  else              asm volatile("global_load_dword %0, %1, off sc0"     : "=v"(r) : "v"(p));
  return r;
}
template<bool S1> __device__ __forceinline__ void stw(uint32_t* p, uint32_t v) {
  if constexpr (S1) asm volatile("global_store_dword %0, %1, off sc0 sc1" :: "v"(p), "v"(v) : "memory");
  else              asm volatile("global_store_dword %0, %1, off sc0"     :: "v"(p), "v"(v) : "memory");
}
template<bool S1> __device__ __forceinline__ void gstore8(short* p, int2 v) {
  if constexpr (S1) asm volatile("global_store_dwordx2 %0, %1, off sc0 sc1" :: "v"(p), "v"(v) : "memory");
  else              asm volatile("global_store_dwordx2 %0, %1, off sc0"     :: "v"(p), "v"(v) : "memory");
}
__device__ __forceinline__ void vdrain() {
  asm volatile("s_waitcnt vmcnt(0)" ::: "memory");
}
__device__ __forceinline__ void vwait0() {
  asm volatile("s_waitcnt vmcnt(0)" ::: "memory");
  __builtin_amdgcn_sched_barrier(0);   // rule #18: keep MFMAs behind the wait
}

// ---------------- layer 0 ----------------
template<bool FAST>
__device__ __forceinline__ void run_l0(
    const float* __restrict__ x, const float* __restrict__ Wih,
    const float* __restrict__ Whh, const float* __restrict__ bih,
    const float* __restrict__ bhh, uint8_t* __restrict__ ws,
    int g, int cp, int l, short* pub)
{
  const int lane15 = l & 15, lgrp = l >> 4;
  const int jg = cp * 16 + lane15;
  const int fidx = cp >> 1, half = cp & 1;
  short* ys = (short*)(ws + YS_OFF);
  uint32_t* tagline = (uint32_t*)(ws + TAG0_OFF + (size_t)g * 128);
  uint32_t* mycell  = tagline + cp;
  const uint32_t* pollc = tagline + lane15;

  const float biR = bih[jg], biZ = bih[HH + jg], biN = bih[2*HH + jg];
  const float bhR = bhh[jg], bhZ = bhh[HH + jg], bhN = bhh[2*HH + jg];

  bh8 whhF[3][8];
#pragma unroll
  for (int gi = 0; gi < 3; ++gi) {
    int grow = gi * HH + jg;
#pragma unroll
    for (int kf = 0; kf < 8; ++kf) {
      const float* p = Whh + (size_t)grow * HH + kf * 32 + lgrp * 8;
      whhF[gi][kf] = cvt8(*(const f4v*)p, *(const f4v*)(p + 4));
    }
  }
  bh8 wihF[3][2];
#pragma unroll
  for (int gi = 0; gi < 3; ++gi) {
    int grow = gi * HH + jg;
#pragma unroll
    for (int kf = 0; kf < 2; ++kf) {
      const float* p = Wih + (size_t)grow * DD + kf * 32 + lgrp * 8;
      wihF[gi][kf] = cvt8(*(const f4v*)p, *(const f4v*)(p + 4));
    }
  }

  const float* xp0 = x + ((size_t)0 * BB + g * 16 + lane15) * DD + lgrp * 8;
  f4v px0 = *(const f4v*)xp0,        px1 = *(const f4v*)(xp0 + 4);
  f4v px2 = *(const f4v*)(xp0 + 32), px3 = *(const f4v*)(xp0 + 36);

  float hp[4] = {0.f, 0.f, 0.f, 0.f};

  for (int t = 0; t < SS; ++t) {
    f4v nx0, nx1, nx2, nx3;
    if (t + 1 < SS) {
      const float* xp = x + ((size_t)(t+1) * BB + g * 16 + lane15) * DD + lgrp * 8;
      nx0 = *(const f4v*)xp;        nx1 = *(const f4v*)(xp + 4);
      nx2 = *(const f4v*)(xp + 32); nx3 = *(const f4v*)(xp + 36);
    }
    bh8 af[8];
    if (t > 0) {
      const uint32_t need = (uint32_t)t;
      for (;;) {
        uint32_t v = ldw<!FAST>(pollc);
        vdrain();
        if (((~__ballot(v >= need)) & 0xFFFFull) == 0ull) break;
      }
      __builtin_amdgcn_sched_barrier(0);
      const short* asrc = ys + ((size_t)(t - 1) * NG + g) * 4096;
#pragma unroll
      for (int kf = 0; kf < 8; ++kf) af[kf] = gload<!FAST>(asrc + kf * 512 + l * 8);
    }
    fx4 accR = {0,0,0,0}, accZ = {0,0,0,0}, accXN = {0,0,0,0}, accHN = {0,0,0,0};
    bh8 xf0 = cvt8(px0, px1), xf1 = cvt8(px2, px3);
    accR  = mfma16(xf0, wihF[0][0], accR);  accR  = mfma16(xf1, wihF[0][1], accR);
    accZ  = mfma16(xf0, wihF[1][0], accZ);  accZ  = mfma16(xf1, wihF[1][1], accZ);
    accXN = mfma16(xf0, wihF[2][0], accXN); accXN = mfma16(xf1, wihF[2][1], accXN);
    vwait0();
    if (t > 0) {
#pragma unroll
      for (int kf = 0; kf < 8; ++kf) {
        accR  = mfma16(af[kf], whhF[0][kf], accR);
        accZ  = mfma16(af[kf], whhF[1][kf], accZ);
        accHN = mfma16(af[kf], whhF[2][kf], accHN);
      }
    }
    px0 = nx0; px1 = nx1; px2 = nx2; px3 = nx3;
#pragma unroll
    for (int i = 0; i < 4; ++i) {
      float r = sigm_(accR[i] + biR + bhR);
      float z = sigm_(accZ[i] + biZ + bhZ);
      float n = tanh_(accXN[i] + biN + r * (accHN[i] + bhN));
      float h = (1.0f - z) * n + z * hp[i];
      short hb = f2bf(h);
      hp[i] = bf2f(hb);
      pub[(lgrp * 4 + i + ((lane15 >> 3) << 4)) * 8 + (lane15 & 7)] = hb;
    }
    __syncthreads();
    int2 v = *(const int2*)&pub[l * 4];
    short* dst = ys + (((size_t)t * NG + g) * 8 + fidx) * 512 + half * 256 + l * 4;
    gstore8<!FAST>(dst, v);
    vdrain();                                   // data visible (L2 or MALL) ...
    if (l == 0) stw<!FAST>(mycell, (uint32_t)(t + 1));   // ... before tag
    __syncthreads();
  }
}

// ---------------- layer 1 ----------------
template<bool FAST>
__device__ __forceinline__ void run_l1(
    const float* __restrict__ Wih, const float* __restrict__ Whh,
    const float* __restrict__ bih, const float* __restrict__ bhh,
    uint8_t* __restrict__ ws, int g, int cp, int l, short* pub)
{
  const int lane15 = l & 15, lgrp = l >> 4;
  const int jg = cp * 16 + lane15;
  const int fidx = cp >> 1, half = cp & 1;
  short* ys   = (short*)(ws + YS_OFF);
  short* ring = (short*)(ws + RING_OFF);
  uint32_t* tag0line = (uint32_t*)(ws + TAG0_OFF + (size_t)g * 128);
  uint32_t* tag1line = (uint32_t*)(ws + TAG1_OFF + (size_t)g * 128);
  uint32_t* mycell   = tag1line + cp;
  const int p = l & 31;
  const uint32_t* pollc = (p < 16) ? (tag0line + p) : (tag1line + (p - 16));

  const float biR = bih[jg], biZ = bih[HH + jg], biN = bih[2*HH + jg];
  const float bhR = bhh[jg], bhZ = bhh[HH + jg], bhN = bhh[2*HH + jg];

  bh8 whhF[3][8], wihF[3][8];
#pragma unroll
  for (int gi = 0; gi < 3; ++gi) {
    int grow = gi * HH + jg;
#pragma unroll
    for (int kf = 0; kf < 8; ++kf) {
      const float* pw = Whh + (size_t)grow * HH + kf * 32 + lgrp * 8;
      whhF[gi][kf] = cvt8(*(const f4v*)pw, *(const f4v*)(pw + 4));
      const float* q = Wih + (size_t)grow * HH + kf * 32 + lgrp * 8;
      wihF[gi][kf] = cvt8(*(const f4v*)q, *(const f4v*)(q + 4));
    }
  }

  float hp[4] = {0.f, 0.f, 0.f, 0.f};

  for (int t = 0; t < SS; ++t) {
    // combined poll: lanes0-15 need tag0 >= t+1 (ys[t] ready);
    //                lanes16-31 need tag1 >= t (ring[t-1] ready; t=0 auto-pass)
    const uint32_t nd = (p < 16) ? (uint32_t)(t + 1) : (uint32_t)t;
    for (;;) {
      uint32_t v = ldw<!FAST>(pollc);
      vdrain();
      if (((~__ballot(v >= nd)) & 0xFFFFFFFFull) == 0ull) break;
    }
    __builtin_amdgcn_sched_barrier(0);
    const short* xsrc = ys + ((size_t)t * NG + g) * 4096;
    bh8 xf[8];
#pragma unroll
    for (int kf = 0; kf < 8; ++kf) xf[kf] = gload<!FAST>(xsrc + kf * 512 + l * 8);
    bh8 af[8];
    if (t > 0) {
      const short* asrc = ring + ((size_t)((t - 1) & 1) * NG + g) * 4096;
#pragma unroll
      for (int kf = 0; kf < 8; ++kf) af[kf] = gload<!FAST>(asrc + kf * 512 + l * 8);
    }
    vwait0();
    fx4 accR = {0,0,0,0}, accZ = {0,0,0,0}, accXN = {0,0,0,0}, accHN = {0,0,0,0};
#pragma unroll
    for (int kf = 0; kf < 8; ++kf) {
      accR  = mfma16(xf[kf], wihF[0][kf], accR);
      accZ  = mfma16(xf[kf], wihF[1][kf], accZ);
      accXN = mfma16(xf[kf], wihF[2][kf], accXN);
    }
    if (t > 0) {
#pragma unroll
      for (int kf = 0; kf < 8; ++kf) {
        accR  = mfma16(af[kf], whhF[0][kf], accR);
        accZ  = mfma16(af[kf], whhF[1][kf], accZ);
        accHN = mfma16(af[kf], whhF[2][kf], accHN);
      }
    }
#pragma unroll
    for (int i = 0; i < 4; ++i) {
      float r = sigm_(accR[i] + biR + bhR);
      float z = sigm_(accZ[i] + biZ + bhZ);
      float n = tanh_(accXN[i] + biN + r * (accHN[i] + bhN));
      float h = (1.0f - z) * n + z * hp[i];
      short hb = f2bf(h);
      hp[i] = bf2f(hb);
      pub[(lgrp * 4 + i + ((lane15 >> 3) << 4)) * 8 + (lane15 & 7)] = hb;
    }
    __syncthreads();
    int2 v = *(const int2*)&pub[l * 4];
    short* dst = ring + (((size_t)(t & 1) * NG + g) * 8 + fidx) * 512 + half * 256 + l * 4;
    gstore8<!FAST>(dst, v);
    vdrain();
    if (l == 0) stw<!FAST>(mycell, (uint32_t)(t + 1));
    __syncthreads();
  }
}

__global__ __launch_bounds__(64, 1) void gru_rec(
    const float* __restrict__ x,
    const float* __restrict__ Wih0, const float* __restrict__ Whh0,
    const float* __restrict__ bih0, const float* __restrict__ bhh0,
    const float* __restrict__ Wih1, const float* __restrict__ Whh1,
    const float* __restrict__ bih1, const float* __restrict__ bhh1,
    uint8_t* __restrict__ ws)
{
  const int l   = threadIdx.x;
  const int bid = blockIdx.x;
  const int layer = bid >> 8, r8 = bid & 255;
  const int g = r8 & 15, cp = r8 >> 4;

  __shared__ short pub[256];

  // ---- bounded sc0-only co-location probe + unanimous vote (proven path) ----
  uint32_t* vote = (uint32_t*)(ws + VOTE_OFF);
  uint32_t* prb  = (uint32_t*)(ws + PRB_OFF);
  const int p  = l & 31;
  const int pb = ((p >> 4) << 8) | ((p & 15) << 4) | g;   // 32 peer blocks of group g
  uint32_t* mine = prb + (size_t)bid * 32;                // 128B-padded cells
  const uint32_t* peerc = prb + (size_t)pb * 32;

  bool okf = true;
  for (int r = 1; r <= 6 && okf; ++r) {
    if (l == 0) stw<false>(mine, (uint32_t)r);
    vdrain();
    const int bound = (r == 1) ? 20000 : 2000;
    bool done = false;
    for (int it = 0; it < bound; ++it) {
      uint32_t v = ldw<false>(peerc);
      vdrain();
      if (((~__ballot(v >= (uint32_t)r)) & 0xFFFFFFFFull) == 0ull) { done = true; break; }
    }
    okf = done;
  }
  if (l == 0) stw<true>(vote + bid, okf ? 2u : 1u);
  vdrain();
  bool fast = false;
  for (;;) {
    uint32_t v = ldw<true>(vote + pb);
    vdrain();
    if (((~__ballot(v != 0u)) & 0xFFFFFFFFull) == 0ull) {
      fast = (((~__ballot(v == 2u)) & 0xFFFFFFFFull) == 0ull);
      break;
    }
  }

  if (layer == 0) {
    if (fast) run_l0<true >(x, Wih0, Whh0, bih0, bhh0, ws, g, cp, l, pub);
    else      run_l0<false>(x, Wih0, Whh0, bih0, bhh0, ws, g, cp, l, pub);
  } else {
    if (fast) run_l1<true >(Wih1, Whh1, bih1, bhh1, ws, g, cp, l, pub);
    else      run_l1<false>(Wih1, Whh1, bih1, bhh1, ws, g, cp, l, pub);
  }
}

__global__ __launch_bounds__(512) void gru_out(
    const uint8_t* __restrict__ ws,
    const float* __restrict__ Wout, const float* __restrict__ bout,
    float* __restrict__ out)
{
  const short* ys   = (const short*)(ws + YS_OFF);
  const short* ring = (const short*)(ws + RING_OFF);
  int bid = blockIdx.x;        // 0..31
  int layer = bid >> 4, g = bid & 15;
  int tid = threadIdx.x;       // 0..511
  int row = tid >> 5, o = tid & 31;
  const short* src = layer ? (ring + ((size_t)1 * NG + g) * 4096)
                           : (ys + ((size_t)2047 * NG + g) * 4096);
  float acc = 0.f;
#pragma unroll 8
  for (int h = 0; h < HH; ++h) {
    int f = h >> 5, lane = row + ((h & 31) >> 3) * 16, idx = h & 7;
    acc += bf2f(src[(size_t)f * 512 + lane * 8 + idx]) * Wout[o * HH + h];
  }
  out[((size_t)(layer * BB) + g * 16 + row) * 32 + o] = tanh_(acc + bout[o]);
}

extern "C" void kernel_launch(void* const* d_in, const int* in_sizes, int n_in,
                              void* d_out, int out_size, void* d_ws, size_t ws_size,
                              hipStream_t stream) {
  const float* x    = (const float*)d_in[0];
  const float* Wih0 = (const float*)d_in[1];
  const float* Whh0 = (const float*)d_in[2];
  const float* bih0 = (const float*)d_in[3];
  const float* bhh0 = (const float*)d_in[4];
  const float* Wih1 = (const float*)d_in[5];
  const float* Whh1 = (const float*)d_in[6];
  const float* bih1 = (const float*)d_in[7];
  const float* bhh1 = (const float*)d_in[8];
  const float* Wout = (const float*)d_in[9];
  const float* bout = (const float*)d_in[10];
  uint8_t* ws = (uint8_t*)d_ws;

  if (ws_size < WS_NEED) return;  // need ~269 MB of scratch

  hipMemsetAsync(ws, 0, MEMSET_SZ, stream);   // votes + tags + probe cells
  gru_rec<<<dim3(512), dim3(64), 0, stream>>>(x, Wih0, Whh0, bih0, bhh0,
                                              Wih1, Whh1, bih1, bhh1, ws);
  gru_out<<<dim3(32), dim3(512), 0, stream>>>(ws, Wout, bout, (float*)d_out);
}

// Round 6
// 3679.769 us; speedup vs baseline: 1.5779x; 1.5779x over previous
//
#include <hip/hip_runtime.h>
#include <stdint.h>

#define HH 256
#define SS 2048
#define BB 256
#define DD 64
#define CHS 32
#define RING 8

typedef __attribute__((ext_vector_type(8))) short bh8;
typedef __attribute__((ext_vector_type(4))) float fx4;
typedef __attribute__((ext_vector_type(4))) float f4v;

// ---------------- ws layout (bytes) ----------------
#define L0TAG_OFF 0ull          // 16 groups x 128B  (steps completed by L0)
#define L1TAG_OFF 2048ull       // 16 groups x 128B
#define P0TAG_OFF 4096ull       // [16 g][64 c] u32  (xp0 chunk ready)
#define P1TAG_OFF 8192ull       // [16 g][64 c] u32
#define BF0_OFF   12288ull      // 768 f32 folded biases layer0
#define BF1_OFF   16384ull      // 768 f32 layer1
#define FIN_OFF   20480ull      // [2 layer][16 g][8 frag][512 short] = 256KB
#define WBF0_OFF  524288ull     // Wih0 frags: 96 x 1KB
#define WBF1_OFF  1048576ull    // Wih1 frags: 384 x 1KB
#define YS_OFF    2097152ull    // ring [8 slot][16 g][32 tl][8 kf][512 short] = 32MB
#define XP0_OFF   37748736ull   // ring [8 slot][16 g][32 tl][48 fid][64][4] bf16 = 96MB
#define XP1_OFF   139460608ull  // 96MB
#define WS_NEED   (XP1_OFF + 100663296ull)   // ~229MB

__device__ __forceinline__ short f2bf(float f) {
  uint32_t u = __builtin_bit_cast(uint32_t, f);
  u += 0x7FFFu + ((u >> 16) & 1u);
  return (short)(u >> 16);
}
__device__ __forceinline__ float bf2f(short s) {
  uint32_t u = ((uint32_t)(uint16_t)s) << 16;
  return __builtin_bit_cast(float, u);
}
__device__ __forceinline__ float lof(int u) {
  return __builtin_bit_cast(float, (uint32_t)u << 16);
}
__device__ __forceinline__ float hif(int u) {
  return __builtin_bit_cast(float, (uint32_t)u & 0xFFFF0000u);
}
__device__ __forceinline__ uint32_t pack2(float a, float b) {
  return ((uint32_t)(uint16_t)f2bf(a)) | (((uint32_t)(uint16_t)f2bf(b)) << 16);
}
__device__ __forceinline__ float rcp_(float x) { return __builtin_amdgcn_rcpf(x); }
__device__ __forceinline__ float tanh_(float x) {
  x = fminf(fmaxf(x, -15.f), 15.f);
  float e = __expf(2.0f * x);
  return (e - 1.0f) / (e + 1.0f);
}
__device__ __forceinline__ fx4 mfma16(bh8 a, bh8 b, fx4 c) {
  return __builtin_amdgcn_mfma_f32_16x16x32_bf16(a, b, c, 0, 0, 0);
}
__device__ __forceinline__ bh8 cvt8(f4v a, f4v b) {
  bh8 r;
  r[0]=f2bf(a[0]); r[1]=f2bf(a[1]); r[2]=f2bf(a[2]); r[3]=f2bf(a[3]);
  r[4]=f2bf(b[0]); r[5]=f2bf(b[1]); r[6]=f2bf(b[2]); r[7]=f2bf(b[3]);
  return r;
}
__device__ __forceinline__ bh8 gld16_cc(const short* p) {
  bh8 r; asm volatile("global_load_dwordx4 %0, %1, off sc0 sc1" : "=v"(r) : "v"(p));
  return r;
}
__device__ __forceinline__ void stw_cc(uint32_t* p, uint32_t v) {
  asm volatile("global_store_dword %0, %1, off sc0 sc1" :: "v"(p), "v"(v) : "memory");
}
__device__ __forceinline__ void vwait0() {
  asm volatile("s_waitcnt vmcnt(0)" ::: "memory");
  __builtin_amdgcn_sched_barrier(0);
}
__device__ __forceinline__ void vwait1() {
  asm volatile("s_waitcnt vmcnt(1)" ::: "memory");
  __builtin_amdgcn_sched_barrier(0);
}
template<int SLP>
__device__ __forceinline__ void wait_nz_cc(const uint32_t* p) {
  for (;;) {
    uint32_t v;
    asm volatile("global_load_dword %0, %1, off sc0 sc1" : "=v"(v) : "v"(p));
    asm volatile("s_waitcnt vmcnt(0)" ::: "memory");
    if (v != 0u) break;
    __builtin_amdgcn_s_sleep(SLP);
  }
  __builtin_amdgcn_sched_barrier(0);
}
template<int SLP>
__device__ __forceinline__ void wait_ge_cc(const uint32_t* p, uint32_t need) {
  for (;;) {
    uint32_t v;
    asm volatile("global_load_dword %0, %1, off sc0 sc1" : "=v"(v) : "v"(p));
    asm volatile("s_waitcnt vmcnt(0)" ::: "memory");
    if (v >= need) break;
    __builtin_amdgcn_s_sleep(SLP);
  }
  __builtin_amdgcn_sched_barrier(0);
}

// issue 6 xp loads (R,Z,N for 2 col-tiles of wave w) for step T
#define ISSUE_XP(T) \
  { const short* b_ = xp + ((size_t)(((((T) >> 5) & 7))*16 + g)*32 + ((T) & 31))*12288 + w*1536 + l*4; \
    asm volatile("global_load_dwordx2 %0, %1, off sc0 sc1"             : "=v"(xA) : "v"(b_)); \
    asm volatile("global_load_dwordx2 %0, %1, off offset:512 sc0 sc1"  : "=v"(xB) : "v"(b_)); \
    asm volatile("global_load_dwordx2 %0, %1, off offset:1024 sc0 sc1" : "=v"(xC) : "v"(b_)); \
    asm volatile("global_load_dwordx2 %0, %1, off offset:1536 sc0 sc1" : "=v"(xD) : "v"(b_)); \
    asm volatile("global_load_dwordx2 %0, %1, off offset:2048 sc0 sc1" : "=v"(xE) : "v"(b_)); \
    asm volatile("global_load_dwordx2 %0, %1, off offset:2560 sc0 sc1" : "=v"(xF) : "v"(b_)); }

// one column-tile: MFMA over K=256 + gates + publish to LDS
#define CTL_BODY(CTL, PR, PZ, PN, BHN)                                           \
  {                                                                              \
    fx4 accR, accZ, accN;                                                        \
    accR[0]=lof(PR.x); accR[1]=hif(PR.x); accR[2]=lof(PR.y); accR[3]=hif(PR.y);  \
    accZ[0]=lof(PZ.x); accZ[1]=hif(PZ.x); accZ[2]=lof(PZ.y); accZ[3]=hif(PZ.y);  \
    float xn0=lof(PN.x), xn1=hif(PN.x), xn2=lof(PN.y), xn3=hif(PN.y);            \
    accN[0]=0.f; accN[1]=0.f; accN[2]=0.f; accN[3]=0.f;                          \
    _Pragma("unroll")                                                            \
    for (int kf = 0; kf < 8; ++kf) {                                             \
      bh8 a = *(const bh8*)&pubp[rb + kf*512 + l*8];                             \
      accR = mfma16(a, whhF[CTL][0][kf], accR);                                  \
      accZ = mfma16(a, whhF[CTL][1][kf], accZ);                                  \
      accN = mfma16(a, whhF[CTL][2][kf], accN);                                  \
    }                                                                            \
    _Pragma("unroll")                                                            \
    for (int i = 0; i < 4; ++i) {                                                \
      float xnv = (i==0)?xn0:((i==1)?xn1:((i==2)?xn2:xn3));                      \
      float r = rcp_(1.0f + __expf(-accR[i]));                                   \
      float z = rcp_(1.0f + __expf(-accZ[i]));                                   \
      float na = xnv + r * (accN[i] + (BHN));                                    \
      float n = 1.0f - 2.0f * rcp_(__expf(2.0f*na) + 1.0f);                      \
      float h = n + z * (hp[(CTL)*4+i] - n);                                     \
      hp[(CTL)*4+i] = h;                                                         \
      int la = lg*4 + i + 16*((CTL)*2 + b3);                                     \
      pubp[wb + la*8 + j7] = f2bf(h);                                            \
    }                                                                            \
  }

// ---------------- recurrent block: one (layer, 16-row group) per CU ----------
template<int LAYER>
__device__ __forceinline__ void run_rec(
    const float* __restrict__ Whh, const float* __restrict__ bhh,
    uint8_t* __restrict__ ws, int g, short* pubp)
{
  const int tid = threadIdx.x;
  const int w = tid >> 6, l = tid & 63;
  const int l15 = l & 15, lg = l >> 4;
  const int b3 = l15 >> 3, j7 = l & 7;

  for (int i = tid; i < 8192; i += 512) pubp[i] = 0;

  bh8 whhF[2][3][8];
#pragma unroll
  for (int ctl = 0; ctl < 2; ++ctl) {
    const int col = (2*w + ctl)*16 + l15;
#pragma unroll
    for (int gate = 0; gate < 3; ++gate) {
      const float* base = Whh + (size_t)(gate*HH + col)*HH;
#pragma unroll
      for (int kf = 0; kf < 8; ++kf) {
        const float* p = base + kf*32 + lg*8;
        whhF[ctl][gate][kf] = cvt8(*(const f4v*)p, *(const f4v*)(p + 4));
      }
    }
  }
  const float bhN0 = bhh[2*HH + (2*w + 0)*16 + l15];
  const float bhN1 = bhh[2*HH + (2*w + 1)*16 + l15];

  uint32_t* mytag       = (uint32_t*)(ws + (LAYER ? L1TAG_OFF : L0TAG_OFF) + (size_t)g*128);
  const uint32_t* ptag  = (const uint32_t*)(ws + (LAYER ? P1TAG_OFF : P0TAG_OFF)) + g*64;
  const uint32_t* bptag = (const uint32_t*)(ws + P1TAG_OFF) + g*64;   // L0 ring bp
  short* xp  = (short*)(ws + (LAYER ? XP1_OFF : XP0_OFF));
  short* ys  = (short*)(ws + YS_OFF);
  short* fin = (short*)(ws + FIN_OFF);

  __syncthreads();

  wait_nz_cc<1>(ptag);
  int2 xA, xB, xC, xD, xE, xF;
  ISSUE_XP(0);
  float hp[8] = {0,0,0,0,0,0,0,0};

  for (int t = 0; t < SS; ++t) {
    const int buf = t & 1;
    const int rb = (buf ^ 1)*4096;       // read prev h frags
    const int wb = buf*4096 + w*512;     // write my frag
    if (LAYER == 0 && (t & (CHS-1)) != 0) vwait1(); else vwait0();

    CTL_BODY(0, xA, xB, xC, bhN0)
    CTL_BODY(1, xD, xE, xF, bhN1)

    const int tn = t + 1;
    if (tn < SS) {
      if ((tn & (CHS-1)) == 0) {
        wait_nz_cc<2>(ptag + (tn >> 5));
        if (LAYER == 0 && (tn >> 5) >= RING) wait_nz_cc<2>(bptag + ((tn >> 5) - RING));
      }
      ISSUE_XP(tn);
    }
    if (LAYER == 0) {
      bh8 mf = *(const bh8*)&pubp[buf*4096 + w*512 + l*8];
      short* dst = ys + ((size_t)(((t >> 5) & 7)*16 + g)*32 + (t & 31))*4096 + w*512 + l*8;
      asm volatile("global_store_dwordx4 %0, %1, off sc0 sc1" :: "v"(dst), "v"(mf) : "memory");
    }
    __syncthreads();
    if ((tn & (CHS-1)) == 0) {
      asm volatile("s_waitcnt vmcnt(0)" ::: "memory");
      __syncthreads();
      if (tid == 0) stw_cc(mytag, (uint32_t)tn);
    }
  }
  // final h frags for out-projection
  bh8 mf = *(const bh8*)&pubp[4096 + w*512 + l*8];   // buf of t=2047 is 1
  short* dst = fin + ((size_t)(LAYER*16 + g)*8 + w)*512 + l*8;
  asm volatile("global_store_dwordx4 %0, %1, off sc0 sc1" :: "v"(dst), "v"(mf) : "memory");
  asm volatile("s_waitcnt vmcnt(0)" ::: "memory");
}

// ---------------- proj0: xp0[t] = x[t]*Wih0^T + bias (K=64) ----------------
__device__ __forceinline__ void run_proj0(const float* __restrict__ x,
                                          uint8_t* __restrict__ ws, int g, int c)
{
  const int tid = threadIdx.x, w = tid >> 6, l = tid & 63, l15 = l & 15, lg = l >> 4;
  if (c >= RING)
    wait_ge_cc<3>((const uint32_t*)(ws + L0TAG_OFF + (size_t)g*128), (uint32_t)(CHS*(c - RING + 1)));
  bh8 A[4][2];
#pragma unroll
  for (int tt = 0; tt < 4; ++tt) {
    const int t = c*32 + w*4 + tt;
#pragma unroll
    for (int kf = 0; kf < 2; ++kf) {
      const float* p = x + ((size_t)t*BB + g*16 + l15)*DD + kf*32 + lg*8;
      A[tt][kf] = cvt8(*(const f4v*)p, *(const f4v*)(p + 4));
    }
  }
  const bh8* WB = (const bh8*)(ws + WBF0_OFF);
  const float* BF = (const float*)(ws + BF0_OFF);
  short* xp0 = (short*)(ws + XP0_OFF);
  const size_t obase = ((size_t)((c & 7)*16 + g)*32 + w*4)*12288 + l*4;
  for (int ct = 0; ct < 48; ++ct) {
    bh8 B0 = WB[(size_t)(ct*2 + 0)*64 + l];
    bh8 B1 = WB[(size_t)(ct*2 + 1)*64 + l];
    const float bb = BF[(ct >> 4)*256 + (ct & 15)*16 + l15];
    const int fid = (ct & 15)*3 + (ct >> 4);
#pragma unroll
    for (int tt = 0; tt < 4; ++tt) {
      fx4 acc = {0.f, 0.f, 0.f, 0.f};
      acc = mfma16(A[tt][0], B0, acc);
      acc = mfma16(A[tt][1], B1, acc);
      int2 v;
      v.x = (int)pack2(acc[0] + bb, acc[1] + bb);
      v.y = (int)pack2(acc[2] + bb, acc[3] + bb);
      short* dst = xp0 + obase + (size_t)tt*12288 + fid*256;
      asm volatile("global_store_dwordx2 %0, %1, off sc0 sc1" :: "v"(dst), "v"(v) : "memory");
    }
  }
  asm volatile("s_waitcnt vmcnt(0)" ::: "memory");
  __syncthreads();
  if (tid == 0) stw_cc((uint32_t*)(ws + P0TAG_OFF) + g*64 + c, 1u);
}

// ---------------- proj1: xp1[t] = ys0[t]*Wih1^T + bias (K=256) --------------
__device__ __forceinline__ void run_proj1(uint8_t* __restrict__ ws, int g, int c)
{
  const int tid = threadIdx.x, w = tid >> 6, l = tid & 63, l15 = l & 15;
  wait_ge_cc<3>((const uint32_t*)(ws + L0TAG_OFF + (size_t)g*128), (uint32_t)(CHS*(c + 1)));
  if (c >= RING)
    wait_ge_cc<3>((const uint32_t*)(ws + L1TAG_OFF + (size_t)g*128), (uint32_t)(CHS*(c - RING + 1)));
  const short* ys = (const short*)(ws + YS_OFF) + ((size_t)((c & 7)*16 + g)*32)*4096;
  bh8 A[4][8];
#pragma unroll
  for (int tt = 0; tt < 4; ++tt)
#pragma unroll
    for (int kf = 0; kf < 8; ++kf)
      A[tt][kf] = gld16_cc(ys + (size_t)(w*4 + tt)*4096 + kf*512 + l*8);
  asm volatile("s_waitcnt vmcnt(0)" ::: "memory");
  __builtin_amdgcn_sched_barrier(0);
  const bh8* WB = (const bh8*)(ws + WBF1_OFF);
  const float* BF = (const float*)(ws + BF1_OFF);
  short* xp1 = (short*)(ws + XP1_OFF);
  const size_t obase = ((size_t)((c & 7)*16 + g)*32 + w*4)*12288 + l*4;
  for (int ct = 0; ct < 48; ++ct) {
    bh8 B[8];
#pragma unroll
    for (int kf = 0; kf < 8; ++kf) B[kf] = WB[(size_t)(ct*8 + kf)*64 + l];
    const float bb = BF[(ct >> 4)*256 + (ct & 15)*16 + l15];
    const int fid = (ct & 15)*3 + (ct >> 4);
#pragma unroll
    for (int tt = 0; tt < 4; ++tt) {
      fx4 acc = {0.f, 0.f, 0.f, 0.f};
#pragma unroll
      for (int kf = 0; kf < 8; ++kf) acc = mfma16(A[tt][kf], B[kf], acc);
      int2 v;
      v.x = (int)pack2(acc[0] + bb, acc[1] + bb);
      v.y = (int)pack2(acc[2] + bb, acc[3] + bb);
      short* dst = xp1 + obase + (size_t)tt*12288 + fid*256;
      asm volatile("global_store_dwordx2 %0, %1, off sc0 sc1" :: "v"(dst), "v"(v) : "memory");
    }
  }
  asm volatile("s_waitcnt vmcnt(0)" ::: "memory");
  __syncthreads();
  if (tid == 0) stw_cc((uint32_t*)(ws + P1TAG_OFF) + g*64 + c, 1u);
}

// ---------------- kernels ----------------
__global__ __launch_bounds__(512) void gru_prep(
    const float* __restrict__ Wih0, const float* __restrict__ Wih1,
    const float* __restrict__ bih0, const float* __restrict__ bhh0,
    const float* __restrict__ bih1, const float* __restrict__ bhh1,
    uint8_t* __restrict__ ws)
{
  const int bid = blockIdx.x, tid = threadIdx.x;
  if (bid == 60) {
    float* BF0 = (float*)(ws + BF0_OFF);
    float* BF1 = (float*)(ws + BF1_OFF);
    for (int i = tid; i < 768; i += 512) {
      const int gate = i >> 8;
      BF0[i] = bih0[i] + (gate < 2 ? bhh0[i] : 0.f);
      BF1[i] = bih1[i] + (gate < 2 ? bhh1[i] : 0.f);
    }
    return;
  }
  const int W = bid*8 + (tid >> 6), l = tid & 63, l15 = l & 15, lg = l >> 4;
  if (W < 96) {
    const int ct = W >> 1, kf = W & 1;
    const float* p = Wih0 + (size_t)(ct*16 + l15)*DD + kf*32 + lg*8;
    ((bh8*)(ws + WBF0_OFF))[(size_t)W*64 + l] = cvt8(*(const f4v*)p, *(const f4v*)(p + 4));
  } else {
    const int V = W - 96, ct = V >> 3, kf = V & 7;
    const float* p = Wih1 + (size_t)(ct*16 + l15)*HH + kf*32 + lg*8;
    ((bh8*)(ws + WBF1_OFF))[(size_t)V*64 + l] = cvt8(*(const f4v*)p, *(const f4v*)(p + 4));
  }
}

__global__ __launch_bounds__(512, 2) void gru_mega(
    const float* __restrict__ x,
    const float* __restrict__ Whh0, const float* __restrict__ bhh0,
    const float* __restrict__ Whh1, const float* __restrict__ bhh1,
    uint8_t* __restrict__ ws)
{
  __shared__ short pubp[8192];   // [2 buf][8 kf][64 lane][8] h exchange
  const int bid = blockIdx.x;
  if (bid < 16)      run_rec<0>(Whh0, bhh0, ws, bid, pubp);
  else if (bid < 32) run_rec<1>(Whh1, bhh1, ws, bid - 16, pubp);
  else {
    const int j = bid - 32, c = j >> 5, r = j & 31;
    if (r < 16) run_proj0(x, ws, r, c);
    else        run_proj1(ws, r - 16, c);
  }
}

__global__ __launch_bounds__(512) void gru_out(
    const uint8_t* __restrict__ ws,
    const float* __restrict__ Wout, const float* __restrict__ bout,
    float* __restrict__ out)
{
  const short* fin = (const short*)(ws + FIN_OFF);
  const int bid = blockIdx.x;             // 0..31
  const int layer = bid >> 4, g = bid & 15;
  const int tid = threadIdx.x;            // 0..511
  const int row = tid >> 5, o = tid & 31;
  const short* src = fin + (size_t)(layer*16 + g)*4096;
  float acc = 0.f;
#pragma unroll 8
  for (int h = 0; h < HH; ++h) {
    const int f = h >> 5, lane = row + ((h & 31) >> 3)*16, idx = h & 7;
    acc += bf2f(src[f*512 + lane*8 + idx]) * Wout[o*HH + h];
  }
  out[((size_t)(layer*BB) + g*16 + row)*32 + o] = tanh_(acc + bout[o]);
}

extern "C" void kernel_launch(void* const* d_in, const int* in_sizes, int n_in,
                              void* d_out, int out_size, void* d_ws, size_t ws_size,
                              hipStream_t stream) {
  const float* x    = (const float*)d_in[0];
  const float* Wih0 = (const float*)d_in[1];
  const float* Whh0 = (const float*)d_in[2];
  const float* bih0 = (const float*)d_in[3];
  const float* bhh0 = (const float*)d_in[4];
  const float* Wih1 = (const float*)d_in[5];
  const float* Whh1 = (const float*)d_in[6];
  const float* bih1 = (const float*)d_in[7];
  const float* bhh1 = (const float*)d_in[8];
  const float* Wout = (const float*)d_in[9];
  const float* bout = (const float*)d_in[10];
  uint8_t* ws = (uint8_t*)d_ws;

  if (ws_size < WS_NEED) return;   // ~229MB of scratch

  (void)hipMemsetAsync(ws, 0, 16384, stream);   // all tag arrays
  gru_prep<<<dim3(61), dim3(512), 0, stream>>>(Wih0, Wih1, bih0, bhh0, bih1, bhh1, ws);
  gru_mega<<<dim3(2080), dim3(512), 0, stream>>>(x, Whh0, bhh0, Whh1, bhh1, ws);
  gru_out<<<dim3(32), dim3(512), 0, stream>>>(ws, Wout, bout, (float*)d_out);
}

// Round 7
// 3665.535 us; speedup vs baseline: 1.5840x; 1.0039x over previous
//
#include <hip/hip_runtime.h>
#include <stdint.h>

#define HH 256
#define SS 2048
#define BB 256
#define DD 64
#define CHS 32
#define RING 8

typedef __attribute__((ext_vector_type(8))) short bh8;
typedef __attribute__((ext_vector_type(4))) float fx4;
typedef __attribute__((ext_vector_type(4))) float f4v;

// ---------------- ws layout (bytes) ----------------
#define L0TAG_OFF 0ull          // 16 groups x 128B  (steps completed by L0)
#define L1TAG_OFF 2048ull       // 16 groups x 128B
#define P0TAG_OFF 4096ull       // [16 g][64 c] u32  (xp0 chunk ready)
#define P1TAG_OFF 8192ull       // [16 g][64 c] u32
#define BF0_OFF   12288ull      // 768 f32 folded biases layer0
#define BF1_OFF   16384ull      // 768 f32 layer1
#define FIN_OFF   20480ull      // [2 layer][16 g][8 frag][512 short] = 256KB
#define WBF0_OFF  524288ull     // Wih0 frags: 96 x 1KB
#define WBF1_OFF  1048576ull    // Wih1 frags: 384 x 1KB
#define YS_OFF    2097152ull    // ring [8 slot][16 g][32 tl][8 kf][512 short] = 32MB
#define XP0_OFF   37748736ull   // ring [8 slot][16 g][32 tl][48 fid][64][4] bf16 = 96MB
#define XP1_OFF   139460608ull  // 96MB
#define WS_NEED   (XP1_OFF + 100663296ull)   // ~229MB

__device__ __forceinline__ short f2bf(float f) {
  uint32_t u = __builtin_bit_cast(uint32_t, f);
  u += 0x7FFFu + ((u >> 16) & 1u);
  return (short)(u >> 16);
}
__device__ __forceinline__ float bf2f(short s) {
  uint32_t u = ((uint32_t)(uint16_t)s) << 16;
  return __builtin_bit_cast(float, u);
}
__device__ __forceinline__ float lof(int u) {
  return __builtin_bit_cast(float, (uint32_t)u << 16);
}
__device__ __forceinline__ float hif(int u) {
  return __builtin_bit_cast(float, (uint32_t)u & 0xFFFF0000u);
}
__device__ __forceinline__ uint32_t pack2(float a, float b) {
  return ((uint32_t)(uint16_t)f2bf(a)) | (((uint32_t)(uint16_t)f2bf(b)) << 16);
}
__device__ __forceinline__ float rcp_(float x) { return __builtin_amdgcn_rcpf(x); }
__device__ __forceinline__ float tanh_(float x) {
  x = fminf(fmaxf(x, -15.f), 15.f);
  float e = __expf(2.0f * x);
  return (e - 1.0f) / (e + 1.0f);
}
__device__ __forceinline__ fx4 mfma16(bh8 a, bh8 b, fx4 c) {
  return __builtin_amdgcn_mfma_f32_16x16x32_bf16(a, b, c, 0, 0, 0);
}
__device__ __forceinline__ bh8 cvt8(f4v a, f4v b) {
  bh8 r;
  r[0]=f2bf(a[0]); r[1]=f2bf(a[1]); r[2]=f2bf(a[2]); r[3]=f2bf(a[3]);
  r[4]=f2bf(b[0]); r[5]=f2bf(b[1]); r[6]=f2bf(b[2]); r[7]=f2bf(b[3]);
  return r;
}
__device__ __forceinline__ bh8 gld16_cc(const short* p) {
  bh8 r; asm volatile("global_load_dwordx4 %0, %1, off sc0 sc1" : "=v"(r) : "v"(p));
  return r;
}
__device__ __forceinline__ void stw_cc(uint32_t* p, uint32_t v) {
  asm volatile("global_store_dword %0, %1, off sc0 sc1" :: "v"(p), "v"(v) : "memory");
}
__device__ __forceinline__ void vwait0() {
  asm volatile("s_waitcnt vmcnt(0)" ::: "memory");
  __builtin_amdgcn_sched_barrier(0);
}
__device__ __forceinline__ void vwait1() {
  asm volatile("s_waitcnt vmcnt(1)" ::: "memory");
  __builtin_amdgcn_sched_barrier(0);
}
template<int SLP>
__device__ __forceinline__ void wait_nz_cc(const uint32_t* p) {
  for (;;) {
    uint32_t v;
    asm volatile("global_load_dword %0, %1, off sc0 sc1" : "=v"(v) : "v"(p));
    asm volatile("s_waitcnt vmcnt(0)" ::: "memory");
    if (v != 0u) break;
    __builtin_amdgcn_s_sleep(SLP);
  }
  __builtin_amdgcn_sched_barrier(0);
}
template<int SLP>
__device__ __forceinline__ void wait_ge_cc(const uint32_t* p, uint32_t need) {
  for (;;) {
    uint32_t v;
    asm volatile("global_load_dword %0, %1, off sc0 sc1" : "=v"(v) : "v"(p));
    asm volatile("s_waitcnt vmcnt(0)" ::: "memory");
    if (v >= need) break;
    __builtin_amdgcn_s_sleep(SLP);
  }
  __builtin_amdgcn_sched_barrier(0);
}

// issue 6 xp loads (R,Z,N for 2 col-tiles of wave w) for step T
#define ISSUE_XP(T) \
  { const short* b_ = xp + ((size_t)(((((T) >> 5) & 7))*16 + g)*32 + ((T) & 31))*12288 + w*1536 + l*4; \
    asm volatile("global_load_dwordx2 %0, %1, off sc0 sc1"             : "=v"(xA) : "v"(b_)); \
    asm volatile("global_load_dwordx2 %0, %1, off offset:512 sc0 sc1"  : "=v"(xB) : "v"(b_)); \
    asm volatile("global_load_dwordx2 %0, %1, off offset:1024 sc0 sc1" : "=v"(xC) : "v"(b_)); \
    asm volatile("global_load_dwordx2 %0, %1, off offset:1536 sc0 sc1" : "=v"(xD) : "v"(b_)); \
    asm volatile("global_load_dwordx2 %0, %1, off offset:2048 sc0 sc1" : "=v"(xE) : "v"(b_)); \
    asm volatile("global_load_dwordx2 %0, %1, off offset:2560 sc0 sc1" : "=v"(xF) : "v"(b_)); }

// one column-tile: MFMA over K=256 + gates + publish to LDS
#define CTL_BODY(CTL, PR, PZ, PN, BHN)                                           \
  {                                                                              \
    fx4 accR, accZ, accN;                                                        \
    accR[0]=lof(PR.x); accR[1]=hif(PR.x); accR[2]=lof(PR.y); accR[3]=hif(PR.y);  \
    accZ[0]=lof(PZ.x); accZ[1]=hif(PZ.x); accZ[2]=lof(PZ.y); accZ[3]=hif(PZ.y);  \
    float xn0=lof(PN.x), xn1=hif(PN.x), xn2=lof(PN.y), xn3=hif(PN.y);            \
    accN[0]=0.f; accN[1]=0.f; accN[2]=0.f; accN[3]=0.f;                          \
    _Pragma("unroll")                                                            \
    for (int kf = 0; kf < 8; ++kf) {                                             \
      bh8 a = *(const bh8*)&pubp[rb + kf*512 + l*8];                             \
      accR = mfma16(a, whhF[CTL][0][kf], accR);                                  \
      accZ = mfma16(a, whhF[CTL][1][kf], accZ);                                  \
      accN = mfma16(a, whhF[CTL][2][kf], accN);                                  \
    }                                                                            \
    _Pragma("unroll")                                                            \
    for (int i = 0; i < 4; ++i) {                                                \
      float xnv = (i==0)?xn0:((i==1)?xn1:((i==2)?xn2:xn3));                      \
      float r = rcp_(1.0f + __expf(-accR[i]));                                   \
      float z = rcp_(1.0f + __expf(-accZ[i]));                                   \
      float na = xnv + r * (accN[i] + (BHN));                                    \
      float n = 1.0f - 2.0f * rcp_(__expf(2.0f*na) + 1.0f);                      \
      float h = n + z * (hp[(CTL)*4+i] - n);                                     \
      hp[(CTL)*4+i] = h;                                                         \
      int la = lg*4 + i + 16*((CTL)*2 + b3);                                     \
      pubp[wb + la*8 + j7] = f2bf(h);                                            \
    }                                                                            \
  }

// ---------------- recurrent block: one (layer, 16-row group) per CU ----------
template<int LAYER>
__device__ __forceinline__ void run_rec(
    const float* __restrict__ Whh, const float* __restrict__ bhh,
    uint8_t* __restrict__ ws, int g, short* pubp)
{
  const int tid = threadIdx.x;
  const int w = tid >> 6, l = tid & 63;
  const int l15 = l & 15, lg = l >> 4;
  const int b3 = l15 >> 3, j7 = l & 7;

  for (int i = tid; i < 8192; i += 512) pubp[i] = 0;

  bh8 whhF[2][3][8];
#pragma unroll
  for (int ctl = 0; ctl < 2; ++ctl) {
    const int col = (2*w + ctl)*16 + l15;
#pragma unroll
    for (int gate = 0; gate < 3; ++gate) {
      const float* base = Whh + (size_t)(gate*HH + col)*HH;
#pragma unroll
      for (int kf = 0; kf < 8; ++kf) {
        const float* p = base + kf*32 + lg*8;
        whhF[ctl][gate][kf] = cvt8(*(const f4v*)p, *(const f4v*)(p + 4));
      }
    }
  }
  const float bhN0 = bhh[2*HH + (2*w + 0)*16 + l15];
  const float bhN1 = bhh[2*HH + (2*w + 1)*16 + l15];

  uint32_t* mytag       = (uint32_t*)(ws + (LAYER ? L1TAG_OFF : L0TAG_OFF) + (size_t)g*128);
  const uint32_t* ptag  = (const uint32_t*)(ws + (LAYER ? P1TAG_OFF : P0TAG_OFF)) + g*64;
  const uint32_t* bptag = (const uint32_t*)(ws + P1TAG_OFF) + g*64;   // L0 ring bp
  short* xp  = (short*)(ws + (LAYER ? XP1_OFF : XP0_OFF));
  short* ys  = (short*)(ws + YS_OFF);
  short* fin = (short*)(ws + FIN_OFF);

  __syncthreads();

  wait_nz_cc<1>(ptag);
  int2 xA, xB, xC, xD, xE, xF;
  ISSUE_XP(0);
  float hp[8] = {0,0,0,0,0,0,0,0};

  for (int t = 0; t < SS; ++t) {
    const int buf = t & 1;
    const int rb = (buf ^ 1)*4096;       // read prev h frags
    const int wb = buf*4096 + w*512;     // write my frag
    if (LAYER == 0 && (t & (CHS-1)) != 0) vwait1(); else vwait0();

    CTL_BODY(0, xA, xB, xC, bhN0)
    CTL_BODY(1, xD, xE, xF, bhN1)

    const int tn = t + 1;
    if (tn < SS) {
      if ((tn & (CHS-1)) == 0) {
        wait_nz_cc<2>(ptag + (tn >> 5));
        if (LAYER == 0 && (tn >> 5) >= RING) wait_nz_cc<2>(bptag + ((tn >> 5) - RING));
      }
      ISSUE_XP(tn);
    }
    if (LAYER == 0) {
      bh8 mf = *(const bh8*)&pubp[buf*4096 + w*512 + l*8];
      short* dst = ys + ((size_t)(((t >> 5) & 7)*16 + g)*32 + (t & 31))*4096 + w*512 + l*8;
      asm volatile("global_store_dwordx4 %0, %1, off sc0 sc1" :: "v"(dst), "v"(mf) : "memory");
    }
    __syncthreads();
    if ((tn & (CHS-1)) == 0) {
      asm volatile("s_waitcnt vmcnt(0)" ::: "memory");
      __syncthreads();
      if (tid == 0) stw_cc(mytag, (uint32_t)tn);
    }
  }
  // final h frags for out-projection
  bh8 mf = *(const bh8*)&pubp[4096 + w*512 + l*8];   // buf of t=2047 is 1
  short* dst = fin + ((size_t)(LAYER*16 + g)*8 + w)*512 + l*8;
  asm volatile("global_store_dwordx4 %0, %1, off sc0 sc1" :: "v"(dst), "v"(mf) : "memory");
  asm volatile("s_waitcnt vmcnt(0)" ::: "memory");
}

// ---------------- proj0: xp0[t] = x[t]*Wih0^T + bias (K=64) ----------------
__device__ __forceinline__ void run_proj0(const float* __restrict__ x,
                                          uint8_t* __restrict__ ws, int g, int c)
{
  const int tid = threadIdx.x, w = tid >> 6, l = tid & 63, l15 = l & 15, lg = l >> 4;
  if (c >= RING)
    wait_ge_cc<3>((const uint32_t*)(ws + L0TAG_OFF + (size_t)g*128), (uint32_t)(CHS*(c - RING + 1)));
  bh8 A[4][2];
#pragma unroll
  for (int tt = 0; tt < 4; ++tt) {
    const int t = c*32 + w*4 + tt;
#pragma unroll
    for (int kf = 0; kf < 2; ++kf) {
      const float* p = x + ((size_t)t*BB + g*16 + l15)*DD + kf*32 + lg*8;
      A[tt][kf] = cvt8(*(const f4v*)p, *(const f4v*)(p + 4));
    }
  }
  const bh8* WB = (const bh8*)(ws + WBF0_OFF);
  const float* BF = (const float*)(ws + BF0_OFF);
  short* xp0 = (short*)(ws + XP0_OFF);
  const size_t obase = ((size_t)((c & 7)*16 + g)*32 + w*4)*12288 + l*4;
  for (int ct = 0; ct < 48; ++ct) {
    bh8 B0 = WB[(size_t)(ct*2 + 0)*64 + l];
    bh8 B1 = WB[(size_t)(ct*2 + 1)*64 + l];
    const float bb = BF[(ct >> 4)*256 + (ct & 15)*16 + l15];
    const int fid = (ct & 15)*3 + (ct >> 4);
#pragma unroll
    for (int tt = 0; tt < 4; ++tt) {
      fx4 acc = {0.f, 0.f, 0.f, 0.f};
      acc = mfma16(A[tt][0], B0, acc);
      acc = mfma16(A[tt][1], B1, acc);
      int2 v;
      v.x = (int)pack2(acc[0] + bb, acc[1] + bb);
      v.y = (int)pack2(acc[2] + bb, acc[3] + bb);
      short* dst = xp0 + obase + (size_t)tt*12288 + fid*256;
      asm volatile("global_store_dwordx2 %0, %1, off sc0 sc1" :: "v"(dst), "v"(v) : "memory");
    }
  }
  asm volatile("s_waitcnt vmcnt(0)" ::: "memory");
  __syncthreads();
  if (tid == 0) stw_cc((uint32_t*)(ws + P0TAG_OFF) + g*64 + c, 1u);
}

// ---------------- proj1: xp1[t] = ys0[t]*Wih1^T + bias (K=256) --------------
__device__ __forceinline__ void run_proj1(uint8_t* __restrict__ ws, int g, int c)
{
  const int tid = threadIdx.x, w = tid >> 6, l = tid & 63, l15 = l & 15;
  wait_ge_cc<3>((const uint32_t*)(ws + L0TAG_OFF + (size_t)g*128), (uint32_t)(CHS*(c + 1)));
  if (c >= RING)
    wait_ge_cc<3>((const uint32_t*)(ws + L1TAG_OFF + (size_t)g*128), (uint32_t)(CHS*(c - RING + 1)));
  const short* ys = (const short*)(ws + YS_OFF) + ((size_t)((c & 7)*16 + g)*32)*4096;
  bh8 A[4][8];
#pragma unroll
  for (int tt = 0; tt < 4; ++tt)
#pragma unroll
    for (int kf = 0; kf < 8; ++kf)
      A[tt][kf] = gld16_cc(ys + (size_t)(w*4 + tt)*4096 + kf*512 + l*8);
  asm volatile("s_waitcnt vmcnt(0)" ::: "memory");
  __builtin_amdgcn_sched_barrier(0);
  const bh8* WB = (const bh8*)(ws + WBF1_OFF);
  const float* BF = (const float*)(ws + BF1_OFF);
  short* xp1 = (short*)(ws + XP1_OFF);
  const size_t obase = ((size_t)((c & 7)*16 + g)*32 + w*4)*12288 + l*4;
  for (int ct = 0; ct < 48; ++ct) {
    bh8 B[8];
#pragma unroll
    for (int kf = 0; kf < 8; ++kf) B[kf] = WB[(size_t)(ct*8 + kf)*64 + l];
    const float bb = BF[(ct >> 4)*256 + (ct & 15)*16 + l15];
    const int fid = (ct & 15)*3 + (ct >> 4);
#pragma unroll
    for (int tt = 0; tt < 4; ++tt) {
      fx4 acc = {0.f, 0.f, 0.f, 0.f};
#pragma unroll
      for (int kf = 0; kf < 8; ++kf) acc = mfma16(A[tt][kf], B[kf], acc);
      int2 v;
      v.x = (int)pack2(acc[0] + bb, acc[1] + bb);
      v.y = (int)pack2(acc[2] + bb, acc[3] + bb);
      short* dst = xp1 + obase + (size_t)tt*12288 + fid*256;
      asm volatile("global_store_dwordx2 %0, %1, off sc0 sc1" :: "v"(dst), "v"(v) : "memory");
    }
  }
  asm volatile("s_waitcnt vmcnt(0)" ::: "memory");
  __syncthreads();
  if (tid == 0) stw_cc((uint32_t*)(ws + P1TAG_OFF) + g*64 + c, 1u);
}

// ---------------- kernels ----------------
__global__ __launch_bounds__(512) void gru_prep(
    const float* __restrict__ Wih0, const float* __restrict__ Wih1,
    const float* __restrict__ bih0, const float* __restrict__ bhh0,
    const float* __restrict__ bih1, const float* __restrict__ bhh1,
    uint8_t* __restrict__ ws)
{
  const int bid = blockIdx.x, tid = threadIdx.x;
  if (bid == 60) {
    float* BF0 = (float*)(ws + BF0_OFF);
    float* BF1 = (float*)(ws + BF1_OFF);
    for (int i = tid; i < 768; i += 512) {
      const int gate = i >> 8;
      BF0[i] = bih0[i] + (gate < 2 ? bhh0[i] : 0.f);
      BF1[i] = bih1[i] + (gate < 2 ? bhh1[i] : 0.f);
    }
    return;
  }
  const int W = bid*8 + (tid >> 6), l = tid & 63, l15 = l & 15, lg = l >> 4;
  if (W < 96) {
    const int ct = W >> 1, kf = W & 1;
    const float* p = Wih0 + (size_t)(ct*16 + l15)*DD + kf*32 + lg*8;
    ((bh8*)(ws + WBF0_OFF))[(size_t)W*64 + l] = cvt8(*(const f4v*)p, *(const f4v*)(p + 4));
  } else {
    const int V = W - 96, ct = V >> 3, kf = V & 7;
    const float* p = Wih1 + (size_t)(ct*16 + l15)*HH + kf*32 + lg*8;
    ((bh8*)(ws + WBF1_OFF))[(size_t)V*64 + l] = cvt8(*(const f4v*)p, *(const f4v*)(p + 4));
  }
}

__global__ __launch_bounds__(512, 1) void gru_mega(
    const float* __restrict__ x,
    const float* __restrict__ Whh0, const float* __restrict__ bhh0,
    const float* __restrict__ Whh1, const float* __restrict__ bhh1,
    uint8_t* __restrict__ ws)
{
  __shared__ short pubp[8192];   // [2 buf][8 kf][64 lane][8] h exchange
  const int bid = blockIdx.x;
  if (bid < 16)      run_rec<0>(Whh0, bhh0, ws, bid, pubp);
  else if (bid < 32) run_rec<1>(Whh1, bhh1, ws, bid - 16, pubp);
  else {
    const int j = bid - 32, c = j >> 5, r = j & 31;
    if (r < 16) run_proj0(x, ws, r, c);
    else        run_proj1(ws, r - 16, c);
  }
}

__global__ __launch_bounds__(512) void gru_out(
    const uint8_t* __restrict__ ws,
    const float* __restrict__ Wout, const float* __restrict__ bout,
    float* __restrict__ out)
{
  const short* fin = (const short*)(ws + FIN_OFF);
  const int bid = blockIdx.x;             // 0..31
  const int layer = bid >> 4, g = bid & 15;
  const int tid = threadIdx.x;            // 0..511
  const int row = tid >> 5, o = tid & 31;
  const short* src = fin + (size_t)(layer*16 + g)*4096;
  float acc = 0.f;
#pragma unroll 8
  for (int h = 0; h < HH; ++h) {
    const int f = h >> 5, lane = row + ((h & 31) >> 3)*16, idx = h & 7;
    acc += bf2f(src[f*512 + lane*8 + idx]) * Wout[o*HH + h];
  }
  out[((size_t)(layer*BB) + g*16 + row)*32 + o] = tanh_(acc + bout[o]);
}

extern "C" void kernel_launch(void* const* d_in, const int* in_sizes, int n_in,
                              void* d_out, int out_size, void* d_ws, size_t ws_size,
                              hipStream_t stream) {
  const float* x    = (const float*)d_in[0];
  const float* Wih0 = (const float*)d_in[1];
  const float* Whh0 = (const float*)d_in[2];
  const float* bih0 = (const float*)d_in[3];
  const float* bhh0 = (const float*)d_in[4];
  const float* Wih1 = (const float*)d_in[5];
  const float* Whh1 = (const float*)d_in[6];
  const float* bih1 = (const float*)d_in[7];
  const float* bhh1 = (const float*)d_in[8];
  const float* Wout = (const float*)d_in[9];
  const float* bout = (const float*)d_in[10];
  uint8_t* ws = (uint8_t*)d_ws;

  if (ws_size < WS_NEED) return;   // ~229MB of scratch

  (void)hipMemsetAsync(ws, 0, 16384, stream);   // all tag arrays
  gru_prep<<<dim3(61), dim3(512), 0, stream>>>(Wih0, Wih1, bih0, bhh0, bih1, bhh1, ws);
  gru_mega<<<dim3(2080), dim3(512), 0, stream>>>(x, Whh0, bhh0, Whh1, bhh1, ws);
  gru_out<<<dim3(32), dim3(512), 0, stream>>>(ws, Wout, bout, (float*)d_out);
}

// Round 8
// 3581.120 us; speedup vs baseline: 1.6214x; 1.0236x over previous
//
#include <hip/hip_runtime.h>
#include <stdint.h>

#define HH 256
#define SS 2048
#define BB 256
#define DD 64
#define CHS 32
#define RING 8

typedef __attribute__((ext_vector_type(8))) short bh8;
typedef __attribute__((ext_vector_type(4))) float fx4;
typedef __attribute__((ext_vector_type(4))) float f4v;

// ---------------- ws layout (bytes) ----------------
#define L0TAG_OFF 0ull          // 16 groups x 128B  (steps completed by L0)
#define L1TAG_OFF 2048ull       // 16 groups x 128B
#define P0TAG_OFF 4096ull       // [16 g][64 c] u32  (xp0 chunk ready)
#define P1TAG_OFF 8192ull       // [16 g][64 c] u32
#define BF0_OFF   12288ull      // 768 f32 folded biases layer0
#define BF1_OFF   16384ull      // 768 f32 layer1
#define FIN_OFF   20480ull      // [2 layer][16 g][8 frag][512 short] = 256KB
#define WBF0_OFF  524288ull     // Wih0 frags: 96 x 1KB
#define WBF1_OFF  1048576ull    // Wih1 frags: 384 x 1KB
#define YS_OFF    2097152ull    // ring [8 slot][16 g][32 tl][8 kf][512 short] = 32MB
#define XP0_OFF   37748736ull   // ring [8 slot][16 g][32 tl][48 fid][64][4] bf16 = 96MB
#define XP1_OFF   139460608ull  // 96MB
#define WS_NEED   (XP1_OFF + 100663296ull)   // ~229MB

__device__ __forceinline__ short f2bf(float f) {
  uint32_t u = __builtin_bit_cast(uint32_t, f);
  u += 0x7FFFu + ((u >> 16) & 1u);
  return (short)(u >> 16);
}
__device__ __forceinline__ float bf2f(short s) {
  uint32_t u = ((uint32_t)(uint16_t)s) << 16;
  return __builtin_bit_cast(float, u);
}
__device__ __forceinline__ float lof(int u) {
  return __builtin_bit_cast(float, (uint32_t)u << 16);
}
__device__ __forceinline__ float hif(int u) {
  return __builtin_bit_cast(float, (uint32_t)u & 0xFFFF0000u);
}
__device__ __forceinline__ uint32_t pack2(float a, float b) {
  return ((uint32_t)(uint16_t)f2bf(a)) | (((uint32_t)(uint16_t)f2bf(b)) << 16);
}
__device__ __forceinline__ float rcp_(float x) { return __builtin_amdgcn_rcpf(x); }
__device__ __forceinline__ float tanh_(float x) {
  x = fminf(fmaxf(x, -15.f), 15.f);
  float e = __expf(2.0f * x);
  return (e - 1.0f) / (e + 1.0f);
}
__device__ __forceinline__ fx4 mfma16(bh8 a, bh8 b, fx4 c) {
  return __builtin_amdgcn_mfma_f32_16x16x32_bf16(a, b, c, 0, 0, 0);
}
__device__ __forceinline__ bh8 cvt8(f4v a, f4v b) {
  bh8 r;
  r[0]=f2bf(a[0]); r[1]=f2bf(a[1]); r[2]=f2bf(a[2]); r[3]=f2bf(a[3]);
  r[4]=f2bf(b[0]); r[5]=f2bf(b[1]); r[6]=f2bf(b[2]); r[7]=f2bf(b[3]);
  return r;
}
__device__ __forceinline__ bh8 gld16_cc(const short* p) {
  bh8 r; asm volatile("global_load_dwordx4 %0, %1, off sc0 sc1" : "=v"(r) : "v"(p));
  return r;
}
__device__ __forceinline__ void stw_cc(uint32_t* p, uint32_t v) {
  asm volatile("global_store_dword %0, %1, off sc0 sc1" :: "v"(p), "v"(v) : "memory");
}
__device__ __forceinline__ void vwait0() {
  asm volatile("s_waitcnt vmcnt(0)" ::: "memory");
  __builtin_amdgcn_sched_barrier(0);
}
__device__ __forceinline__ void vwait1() {
  asm volatile("s_waitcnt vmcnt(1)" ::: "memory");
  __builtin_amdgcn_sched_barrier(0);
}
template<int SLP>
__device__ __forceinline__ void wait_nz_cc(const uint32_t* p) {
  for (;;) {
    uint32_t v;
    asm volatile("global_load_dword %0, %1, off sc0 sc1" : "=v"(v) : "v"(p));
    asm volatile("s_waitcnt vmcnt(0)" ::: "memory");
    if (v != 0u) break;
    __builtin_amdgcn_s_sleep(SLP);
  }
  __builtin_amdgcn_sched_barrier(0);
}
template<int SLP>
__device__ __forceinline__ void wait_ge_cc(const uint32_t* p, uint32_t need) {
  for (;;) {
    uint32_t v;
    asm volatile("global_load_dword %0, %1, off sc0 sc1" : "=v"(v) : "v"(p));
    asm volatile("s_waitcnt vmcnt(0)" ::: "memory");
    if (v >= need) break;
    __builtin_amdgcn_s_sleep(SLP);
  }
  __builtin_amdgcn_sched_barrier(0);
}

// issue 6 xp loads (R,Z,N for 2 col-tiles of wave w) for step T
#define ISSUE_XP(T) \
  { const short* b_ = xp + ((size_t)(((((T) >> 5) & 7))*16 + g)*32 + ((T) & 31))*12288 + w*1536 + l*4; \
    asm volatile("global_load_dwordx2 %0, %1, off sc0 sc1"             : "=v"(xA) : "v"(b_)); \
    asm volatile("global_load_dwordx2 %0, %1, off offset:512 sc0 sc1"  : "=v"(xB) : "v"(b_)); \
    asm volatile("global_load_dwordx2 %0, %1, off offset:1024 sc0 sc1" : "=v"(xC) : "v"(b_)); \
    asm volatile("global_load_dwordx2 %0, %1, off offset:1536 sc0 sc1" : "=v"(xD) : "v"(b_)); \
    asm volatile("global_load_dwordx2 %0, %1, off offset:2048 sc0 sc1" : "=v"(xE) : "v"(b_)); \
    asm volatile("global_load_dwordx2 %0, %1, off offset:2560 sc0 sc1" : "=v"(xF) : "v"(b_)); }

// one column-tile: MFMA over K=256 + gates + publish to LDS
#define CTL_BODY(CTL, PR, PZ, PN, BHN)                                           \
  {                                                                              \
    fx4 accR, accZ, accN;                                                        \
    accR[0]=lof(PR.x); accR[1]=hif(PR.x); accR[2]=lof(PR.y); accR[3]=hif(PR.y);  \
    accZ[0]=lof(PZ.x); accZ[1]=hif(PZ.x); accZ[2]=lof(PZ.y); accZ[3]=hif(PZ.y);  \
    float xn0=lof(PN.x), xn1=hif(PN.x), xn2=lof(PN.y), xn3=hif(PN.y);            \
    accN[0]=0.f; accN[1]=0.f; accN[2]=0.f; accN[3]=0.f;                          \
    _Pragma("unroll")                                                            \
    for (int kf = 0; kf < 8; ++kf) {                                             \
      bh8 a = *(const bh8*)&pubp[rb + kf*512 + l*8];                             \
      accR = mfma16(a, whhF[CTL][0][kf], accR);                                  \
      accZ = mfma16(a, whhF[CTL][1][kf], accZ);                                  \
      accN = mfma16(a, whhF[CTL][2][kf], accN);                                  \
    }                                                                            \
    _Pragma("unroll")                                                            \
    for (int i = 0; i < 4; ++i) {                                                \
      float xnv = (i==0)?xn0:((i==1)?xn1:((i==2)?xn2:xn3));                      \
      float r = rcp_(1.0f + __expf(-accR[i]));                                   \
      float z = rcp_(1.0f + __expf(-accZ[i]));                                   \
      float na = xnv + r * (accN[i] + (BHN));                                    \
      float n = 1.0f - 2.0f * rcp_(__expf(2.0f*na) + 1.0f);                      \
      float h = n + z * (hp[(CTL)*4+i] - n);                                     \
      hp[(CTL)*4+i] = h;                                                         \
      int la = lg*4 + i + 16*((CTL)*2 + b3);                                     \
      pubp[wb + la*8 + j7] = f2bf(h);                                            \
    }                                                                            \
  }

// ---------------- recurrent block: one (layer, 16-row group) per CU ----------
template<int LAYER>
__device__ __forceinline__ void run_rec(
    const float* __restrict__ Whh, const float* __restrict__ bhh,
    uint8_t* __restrict__ ws, int g, short* pubp)
{
  const int tid = threadIdx.x;
  const int w = tid >> 6, l = tid & 63;
  const int l15 = l & 15, lg = l >> 4;
  const int b3 = l15 >> 3, j7 = l & 7;

  for (int i = tid; i < 8192; i += 512) pubp[i] = 0;

  bh8 whhF[2][3][8];
#pragma unroll
  for (int ctl = 0; ctl < 2; ++ctl) {
    const int col = (2*w + ctl)*16 + l15;
#pragma unroll
    for (int gate = 0; gate < 3; ++gate) {
      const float* base = Whh + (size_t)(gate*HH + col)*HH;
#pragma unroll
      for (int kf = 0; kf < 8; ++kf) {
        const float* p = base + kf*32 + lg*8;
        whhF[ctl][gate][kf] = cvt8(*(const f4v*)p, *(const f4v*)(p + 4));
      }
    }
  }
  // pin the 48 weight frags in VGPRs: opaque to rematerialization
#pragma unroll
  for (int ctl = 0; ctl < 2; ++ctl)
#pragma unroll
    for (int gate = 0; gate < 3; ++gate)
#pragma unroll
      for (int kf = 0; kf < 8; ++kf)
        asm volatile("" : "+v"(whhF[ctl][gate][kf]));

  const float bhN0 = bhh[2*HH + (2*w + 0)*16 + l15];
  const float bhN1 = bhh[2*HH + (2*w + 1)*16 + l15];

  uint32_t* mytag       = (uint32_t*)(ws + (LAYER ? L1TAG_OFF : L0TAG_OFF) + (size_t)g*128);
  const uint32_t* ptag  = (const uint32_t*)(ws + (LAYER ? P1TAG_OFF : P0TAG_OFF)) + g*64;
  const uint32_t* bptag = (const uint32_t*)(ws + P1TAG_OFF) + g*64;   // L0 ring bp
  short* xp  = (short*)(ws + (LAYER ? XP1_OFF : XP0_OFF));
  short* ys  = (short*)(ws + YS_OFF);
  short* fin = (short*)(ws + FIN_OFF);

  __syncthreads();

  wait_nz_cc<1>(ptag);
  int2 xA, xB, xC, xD, xE, xF;
  ISSUE_XP(0);
  float hp[8] = {0,0,0,0,0,0,0,0};

  for (int t = 0; t < SS; ++t) {
    const int buf = t & 1;
    const int rb = (buf ^ 1)*4096;       // read prev h frags
    const int wb = buf*4096 + w*512;     // write my frag
    if (LAYER == 0 && (t & (CHS-1)) != 0) vwait1(); else vwait0();

    CTL_BODY(0, xA, xB, xC, bhN0)
    CTL_BODY(1, xD, xE, xF, bhN1)

    const int tn = t + 1;
    if (tn < SS) {
      if ((tn & (CHS-1)) == 0) {
        wait_nz_cc<2>(ptag + (tn >> 5));
        if (LAYER == 0 && (tn >> 5) >= RING) wait_nz_cc<2>(bptag + ((tn >> 5) - RING));
      }
      ISSUE_XP(tn);
    }
    if (LAYER == 0) {
      bh8 mf = *(const bh8*)&pubp[buf*4096 + w*512 + l*8];
      short* dst = ys + ((size_t)(((t >> 5) & 7)*16 + g)*32 + (t & 31))*4096 + w*512 + l*8;
      asm volatile("global_store_dwordx4 %0, %1, off sc0 sc1" :: "v"(dst), "v"(mf) : "memory");
    }
    __syncthreads();
    if ((tn & (CHS-1)) == 0) {
      asm volatile("s_waitcnt vmcnt(0)" ::: "memory");
      __syncthreads();
      if (tid == 0) stw_cc(mytag, (uint32_t)tn);
    }
  }
  // final h frags for out-projection
  bh8 mf = *(const bh8*)&pubp[4096 + w*512 + l*8];   // buf of t=2047 is 1
  short* dst = fin + ((size_t)(LAYER*16 + g)*8 + w)*512 + l*8;
  asm volatile("global_store_dwordx4 %0, %1, off sc0 sc1" :: "v"(dst), "v"(mf) : "memory");
  asm volatile("s_waitcnt vmcnt(0)" ::: "memory");
}

// ---------------- proj0: xp0[t] = x[t]*Wih0^T + bias (K=64) ----------------
__device__ __forceinline__ void run_proj0(const float* __restrict__ x,
                                          uint8_t* __restrict__ ws, int g, int c)
{
  const int tid = threadIdx.x, w = tid >> 6, l = tid & 63, l15 = l & 15, lg = l >> 4;
  if (c >= RING)
    wait_ge_cc<3>((const uint32_t*)(ws + L0TAG_OFF + (size_t)g*128), (uint32_t)(CHS*(c - RING + 1)));
  bh8 A[4][2];
#pragma unroll
  for (int tt = 0; tt < 4; ++tt) {
    const int t = c*32 + w*4 + tt;
#pragma unroll
    for (int kf = 0; kf < 2; ++kf) {
      const float* p = x + ((size_t)t*BB + g*16 + l15)*DD + kf*32 + lg*8;
      A[tt][kf] = cvt8(*(const f4v*)p, *(const f4v*)(p + 4));
    }
  }
  const bh8* WB = (const bh8*)(ws + WBF0_OFF);
  const float* BF = (const float*)(ws + BF0_OFF);
  short* xp0 = (short*)(ws + XP0_OFF);
  const size_t obase = ((size_t)((c & 7)*16 + g)*32 + w*4)*12288 + l*4;
  for (int ct = 0; ct < 48; ++ct) {
    bh8 B0 = WB[(size_t)(ct*2 + 0)*64 + l];
    bh8 B1 = WB[(size_t)(ct*2 + 1)*64 + l];
    const float bb = BF[(ct >> 4)*256 + (ct & 15)*16 + l15];
    const int fid = (ct & 15)*3 + (ct >> 4);
#pragma unroll
    for (int tt = 0; tt < 4; ++tt) {
      fx4 acc = {0.f, 0.f, 0.f, 0.f};
      acc = mfma16(A[tt][0], B0, acc);
      acc = mfma16(A[tt][1], B1, acc);
      int2 v;
      v.x = (int)pack2(acc[0] + bb, acc[1] + bb);
      v.y = (int)pack2(acc[2] + bb, acc[3] + bb);
      short* dst = xp0 + obase + (size_t)tt*12288 + fid*256;
      asm volatile("global_store_dwordx2 %0, %1, off sc0 sc1" :: "v"(dst), "v"(v) : "memory");
    }
  }
  asm volatile("s_waitcnt vmcnt(0)" ::: "memory");
  __syncthreads();
  if (tid == 0) stw_cc((uint32_t*)(ws + P0TAG_OFF) + g*64 + c, 1u);
}

// ---------------- proj1: xp1[t] = ys0[t]*Wih1^T + bias (K=256) --------------
__device__ __forceinline__ void run_proj1(uint8_t* __restrict__ ws, int g, int c)
{
  const int tid = threadIdx.x, w = tid >> 6, l = tid & 63, l15 = l & 15;
  wait_ge_cc<3>((const uint32_t*)(ws + L0TAG_OFF + (size_t)g*128), (uint32_t)(CHS*(c + 1)));
  if (c >= RING)
    wait_ge_cc<3>((const uint32_t*)(ws + L1TAG_OFF + (size_t)g*128), (uint32_t)(CHS*(c - RING + 1)));
  const short* ys = (const short*)(ws + YS_OFF) + ((size_t)((c & 7)*16 + g)*32)*4096;
  bh8 A[4][8];
#pragma unroll
  for (int tt = 0; tt < 4; ++tt)
#pragma unroll
    for (int kf = 0; kf < 8; ++kf)
      A[tt][kf] = gld16_cc(ys + (size_t)(w*4 + tt)*4096 + kf*512 + l*8);
  asm volatile("s_waitcnt vmcnt(0)" ::: "memory");
  __builtin_amdgcn_sched_barrier(0);
  const bh8* WB = (const bh8*)(ws + WBF1_OFF);
  const float* BF = (const float*)(ws + BF1_OFF);
  short* xp1 = (short*)(ws + XP1_OFF);
  const size_t obase = ((size_t)((c & 7)*16 + g)*32 + w*4)*12288 + l*4;
  for (int ct = 0; ct < 48; ++ct) {
    bh8 B[8];
#pragma unroll
    for (int kf = 0; kf < 8; ++kf) B[kf] = WB[(size_t)(ct*8 + kf)*64 + l];
    const float bb = BF[(ct >> 4)*256 + (ct & 15)*16 + l15];
    const int fid = (ct & 15)*3 + (ct >> 4);
#pragma unroll
    for (int tt = 0; tt < 4; ++tt) {
      fx4 acc = {0.f, 0.f, 0.f, 0.f};
#pragma unroll
      for (int kf = 0; kf < 8; ++kf) acc = mfma16(A[tt][kf], B[kf], acc);
      int2 v;
      v.x = (int)pack2(acc[0] + bb, acc[1] + bb);
      v.y = (int)pack2(acc[2] + bb, acc[3] + bb);
      short* dst = xp1 + obase + (size_t)tt*12288 + fid*256;
      asm volatile("global_store_dwordx2 %0, %1, off sc0 sc1" :: "v"(dst), "v"(v) : "memory");
    }
  }
  asm volatile("s_waitcnt vmcnt(0)" ::: "memory");
  __syncthreads();
  if (tid == 0) stw_cc((uint32_t*)(ws + P1TAG_OFF) + g*64 + c, 1u);
}

// ---------------- kernels ----------------
__global__ __launch_bounds__(512) void gru_prep(
    const float* __restrict__ Wih0, const float* __restrict__ Wih1,
    const float* __restrict__ bih0, const float* __restrict__ bhh0,
    const float* __restrict__ bih1, const float* __restrict__ bhh1,
    uint8_t* __restrict__ ws)
{
  const int bid = blockIdx.x, tid = threadIdx.x;
  if (bid == 60) {
    float* BF0 = (float*)(ws + BF0_OFF);
    float* BF1 = (float*)(ws + BF1_OFF);
    for (int i = tid; i < 768; i += 512) {
      const int gate = i >> 8;
      BF0[i] = bih0[i] + (gate < 2 ? bhh0[i] : 0.f);
      BF1[i] = bih1[i] + (gate < 2 ? bhh1[i] : 0.f);
    }
    return;
  }
  const int W = bid*8 + (tid >> 6), l = tid & 63, l15 = l & 15, lg = l >> 4;
  if (W < 96) {
    const int ct = W >> 1, kf = W & 1;
    const float* p = Wih0 + (size_t)(ct*16 + l15)*DD + kf*32 + lg*8;
    ((bh8*)(ws + WBF0_OFF))[(size_t)W*64 + l] = cvt8(*(const f4v*)p, *(const f4v*)(p + 4));
  } else {
    const int V = W - 96, ct = V >> 3, kf = V & 7;
    const float* p = Wih1 + (size_t)(ct*16 + l15)*HH + kf*32 + lg*8;
    ((bh8*)(ws + WBF1_OFF))[(size_t)V*64 + l] = cvt8(*(const f4v*)p, *(const f4v*)(p + 4));
  }
}

__global__ __launch_bounds__(512)
__attribute__((amdgpu_waves_per_eu(2, 2)))
void gru_mega(
    const float* __restrict__ x,
    const float* __restrict__ Whh0, const float* __restrict__ bhh0,
    const float* __restrict__ Whh1, const float* __restrict__ bhh1,
    uint8_t* __restrict__ ws)
{
  __shared__ short pubp[8192];   // [2 buf][8 kf][64 lane][8] h exchange
  const int bid = blockIdx.x;
  if (bid < 16)      run_rec<0>(Whh0, bhh0, ws, bid, pubp);
  else if (bid < 32) run_rec<1>(Whh1, bhh1, ws, bid - 16, pubp);
  else {
    const int j = bid - 32, c = j >> 5, r = j & 31;
    if (r < 16) run_proj0(x, ws, r, c);
    else        run_proj1(ws, r - 16, c);
  }
}

__global__ __launch_bounds__(512) void gru_out(
    const uint8_t* __restrict__ ws,
    const float* __restrict__ Wout, const float* __restrict__ bout,
    float* __restrict__ out)
{
  const short* fin = (const short*)(ws + FIN_OFF);
  const int bid = blockIdx.x;             // 0..31
  const int layer = bid >> 4, g = bid & 15;
  const int tid = threadIdx.x;            // 0..511
  const int row = tid >> 5, o = tid & 31;
  const short* src = fin + (size_t)(layer*16 + g)*4096;
  float acc = 0.f;
#pragma unroll 8
  for (int h = 0; h < HH; ++h) {
    const int f = h >> 5, lane = row + ((h & 31) >> 3)*16, idx = h & 7;
    acc += bf2f(src[f*512 + lane*8 + idx]) * Wout[o*HH + h];
  }
  out[((size_t)(layer*BB) + g*16 + row)*32 + o] = tanh_(acc + bout[o]);
}

extern "C" void kernel_launch(void* const* d_in, const int* in_sizes, int n_in,
                              void* d_out, int out_size, void* d_ws, size_t ws_size,
                              hipStream_t stream) {
  const float* x    = (const float*)d_in[0];
  const float* Wih0 = (const float*)d_in[1];
  const float* Whh0 = (const float*)d_in[2];
  const float* bih0 = (const float*)d_in[3];
  const float* bhh0 = (const float*)d_in[4];
  const float* Wih1 = (const float*)d_in[5];
  const float* Whh1 = (const float*)d_in[6];
  const float* bih1 = (const float*)d_in[7];
  const float* bhh1 = (const float*)d_in[8];
  const float* Wout = (const float*)d_in[9];
  const float* bout = (const float*)d_in[10];
  uint8_t* ws = (uint8_t*)d_ws;

  if (ws_size < WS_NEED) return;   // ~229MB of scratch

  (void)hipMemsetAsync(ws, 0, 16384, stream);   // all tag arrays
  gru_prep<<<dim3(61), dim3(512), 0, stream>>>(Wih0, Wih1, bih0, bhh0, bih1, bhh1, ws);
  gru_mega<<<dim3(2080), dim3(512), 0, stream>>>(x, Whh0, bhh0, Whh1, bhh1, ws);
  gru_out<<<dim3(32), dim3(512), 0, stream>>>(ws, Wout, bout, (float*)d_out);
}